// Round 7
// baseline (1399.693 us; speedup 1.0000x reference)
//
#include <hip/hip_runtime.h>

// EIRNN: B=256,T=512,I=128,H=512,O=64; alpha=0.2, softplus beta=8, thresh=20.
// R8 = R7 + de-atomicized readout. R7 post-mortem: L2-served polls (FETCH
// 1.18GB->170MB) did NOT move dur (1334 vs R2's 1340) -> poll RT was never
// dominant. Step = ~1200cy issue + ~4900cy stall (per-active-CU corrected).
// Remaining suspects: (T1) slow visibility of relaxed sc1 stores, (T3) the
// 4/thread/step device-scope atomicAdd readout RMWs contending at the same
// coherence point AND being drained by the compiler's vmcnt(0) before every
// s_barrier. R8 removes T3 entirely:
//   every block already gathers FULL h_t into LDS, so block c==0 of each
//   group computes the ENTIRE readout (K=512) interleaved into the main
//   MFMA loop -- reusing the SAME A-frags a0/a1 already in registers
//   (+16 MFMA issue in 1/8 blocks, zero extra LDS reads) -- and writes y
//   with PLAIN stores (each element exactly once, no atomics anywhere in
//   the loop). Epilogue iteration t==TT does the last readout standalone.
// Exchange is byte-identical to R7: tagged u64 {hi:tag=t+1, lo:2xf16}
// fire-and-forget sc1 stores; batched sc0 poll rounds (L2-servable) with
// every-4th-round agent fallback (placement-free progress, G16); parity
// double-buffer prevents overwrite-before-consume; own-shard LDS
// short-circuit; 128x256 launch, 1 block/CU.

#define BB 256
#define TT 512
#define II 128
#define HH 512
#define OO 64
#define RG 16   // batch rows per row-group
#define JC 64   // h-columns per shard block
#define NG 16   // row-groups
#define NC 8    // shard blocks per group
#define NB (NG * NC)

typedef _Float16 f16;
typedef f16 f16x8 __attribute__((ext_vector_type(8)));
typedef float f32x4 __attribute__((ext_vector_type(4)));

__global__ __launch_bounds__(256, 1)
void eirnn_persist(const float* __restrict__ x,
                   const float* __restrict__ Wxh,
                   const float* __restrict__ Whh,
                   const float* __restrict__ bh,
                   const float* __restrict__ Wout,
                   const float* __restrict__ bout,
                   float* __restrict__ yout,
                   unsigned long long* __restrict__ hbuf) // 2*(B*H/2) tagged u64
{
    const int tid  = threadIdx.x;
    const int bid  = blockIdx.x;
    const int wave = tid >> 6;
    const int lane = tid & 63;
    const int quad = lane >> 4;
    const int l16  = lane & 15;
    // XCD-clustered mapping (PERF HEURISTIC ONLY: presumed round-robin
    // dispatch xcd=bid&7; correctness is placement-free via agent fallback).
    const int mm   = bid >> 3;                   // 0..15 within presumed XCD
    const int c    = mm >> 1;                    // shard 0..7
    const int r    = (bid & 7) * 2 + (mm & 1);   // group 0..15
    const int rowbase = r * RG;
    const int jbase   = c * JC;
    const int myrow   = wave * 16 + l16;

    // double-buffered by step parity
    __shared__ __align__(16) f16 hg[2][RG][HH + 8];
    __shared__ __align__(16) f16 xsh[2][RG][II + 8];

    // ---- one-time: weight shards -> constant register B-fragments ----
    // B-frag: lane holds BT[n=lane&15][k=quad*8+j], j=0..7 (verified R0)
    f16x8 bf[16];    // W_hh shard, K=512 -> 16 k-steps
    f16x8 xbf[4];    // W_xh shard, K=128 -> 4 k-steps
    f16x8 bfo2[16];  // W_out full-K: wave's n-tile = out cols [wave*16,+16), K=512
    {
        const float* wp = Whh + (size_t)(jbase + myrow) * HH + quad * 8;
        #pragma unroll
        for (int ks = 0; ks < 16; ++ks) {
            float4 u = *(const float4*)(wp + ks * 32);
            float4 v = *(const float4*)(wp + ks * 32 + 4);
            f16x8 tv;
            tv[0]=(f16)u.x; tv[1]=(f16)u.y; tv[2]=(f16)u.z; tv[3]=(f16)u.w;
            tv[4]=(f16)v.x; tv[5]=(f16)v.y; tv[6]=(f16)v.z; tv[7]=(f16)v.w;
            bf[ks] = tv;
        }
        const float* wq = Wxh + (size_t)(jbase + myrow) * II + quad * 8;
        #pragma unroll
        for (int ks = 0; ks < 4; ++ks) {
            float4 u = *(const float4*)(wq + ks * 32);
            float4 v = *(const float4*)(wq + ks * 32 + 4);
            f16x8 tv;
            tv[0]=(f16)u.x; tv[1]=(f16)u.y; tv[2]=(f16)u.z; tv[3]=(f16)u.w;
            tv[4]=(f16)v.x; tv[5]=(f16)v.y; tv[6]=(f16)v.z; tv[7]=(f16)v.w;
            xbf[ks] = tv;
        }
        // W_out is O(64) x H(512); myrow in [0,64) spans all outputs over 4 waves
        const float* wo = Wout + (size_t)myrow * HH + quad * 8;
        #pragma unroll
        for (int ks = 0; ks < 16; ++ks) {
            float4 u = *(const float4*)(wo + ks * 32);
            float4 v = *(const float4*)(wo + ks * 32 + 4);
            f16x8 tv;
            tv[0]=(f16)u.x; tv[1]=(f16)u.y; tv[2]=(f16)u.z; tv[3]=(f16)u.w;
            tv[4]=(f16)v.x; tv[5]=(f16)v.y; tv[6]=(f16)v.z; tv[7]=(f16)v.w;
            bfo2[ks] = tv;
        }
    }
    const float biash = bh[jbase + myrow];
    const float biaso = bout[myrow];   // used by block c==0 only

    // zero hg (t=0 uses h_0 = 0; buffer 1 fully written during iter 0)
    for (int p = tid; p < RG * (HH + 8); p += 256)
        ((unsigned int*)hg)[p] = 0u;

    // fp32 integrator state: lane owns h[m=quad*4+reg][jbase+myrow]
    float hreg[4] = {0.f, 0.f, 0.f, 0.f};

    // gather geometry: thread j8 owns u64-column j8 across 16 rows
    const int j8     = tid;          // 0..255
    const int gshard = j8 >> 5;      // producer shard of this u64-col

    // x prefetch for t=0
    float4 xpf0, xpf1;
    {
        int p0 = tid, p1 = tid + 256;
        xpf0 = ((const float4*)(x + ((size_t)(rowbase + (p0 >> 5)) * TT + 0) * II))[p0 & 31];
        xpf1 = ((const float4*)(x + ((size_t)(rowbase + (p1 >> 5)) * TT + 0) * II))[p1 & 31];
    }

    __syncthreads();

    for (int t = 0; t <= TT; ++t) {
        const int pcur = t & 1;

        // ---- stage x_t from prefetch regs into xsh[pcur] ----
        if (t < TT) {
            int p0 = tid, p1 = tid + 256;
            f16* d0 = &xsh[pcur][p0 >> 5][(p0 & 31) * 4];
            d0[0]=(f16)xpf0.x; d0[1]=(f16)xpf0.y; d0[2]=(f16)xpf0.z; d0[3]=(f16)xpf0.w;
            f16* d1 = &xsh[pcur][p1 >> 5][(p1 & 31) * 4];
            d1[0]=(f16)xpf1.x; d1[1]=(f16)xpf1.y; d1[2]=(f16)xpf1.z; d1[3]=(f16)xpf1.w;
        }
        // ---- issue x_{t+1} prefetch; poll waits absorb it ----
        if (t + 1 < TT) {
            int p0 = tid, p1 = tid + 256;
            xpf0 = ((const float4*)(x + ((size_t)(rowbase + (p0 >> 5)) * TT + (t + 1)) * II))[p0 & 31];
            xpf1 = ((const float4*)(x + ((size_t)(rowbase + (p1 >> 5)) * TT + (t + 1)) * II))[p1 & 31];
        }
        // ---- gather: batched poll rounds, sc0 (L2) with agent fallback ----
        if (t >= 1 && gshard != c) {
            const unsigned long long* src = hbuf
                + (size_t)pcur * (BB * HH / 2)
                + (size_t)rowbase * (HH / 2) + j8;
            const unsigned int tg = (unsigned)t;
            unsigned long long v0, v1, v2, v3, v4, v5, v6, v7;
            unsigned long long v8, v9, v10, v11, v12, v13, v14, v15;
            int round = 0;
            for (;;) {
                if ((round & 3) != 3) {
                    // sc0 batch: L1-bypass, L2-servable, 16 loads in flight
                    asm volatile(
                        "global_load_dwordx2 %0, %8, off sc0\n\t"
                        "global_load_dwordx2 %1, %9, off sc0\n\t"
                        "global_load_dwordx2 %2, %10, off sc0\n\t"
                        "global_load_dwordx2 %3, %11, off sc0\n\t"
                        "global_load_dwordx2 %4, %12, off sc0\n\t"
                        "global_load_dwordx2 %5, %13, off sc0\n\t"
                        "global_load_dwordx2 %6, %14, off sc0\n\t"
                        "global_load_dwordx2 %7, %15, off sc0"
                        : "=&v"(v0), "=&v"(v1), "=&v"(v2), "=&v"(v3),
                          "=&v"(v4), "=&v"(v5), "=&v"(v6), "=&v"(v7)
                        : "v"((unsigned long long)(src)),
                          "v"((unsigned long long)(src + 1 * (HH / 2))),
                          "v"((unsigned long long)(src + 2 * (HH / 2))),
                          "v"((unsigned long long)(src + 3 * (HH / 2))),
                          "v"((unsigned long long)(src + 4 * (HH / 2))),
                          "v"((unsigned long long)(src + 5 * (HH / 2))),
                          "v"((unsigned long long)(src + 6 * (HH / 2))),
                          "v"((unsigned long long)(src + 7 * (HH / 2))));
                    asm volatile(
                        "global_load_dwordx2 %0, %16, off sc0\n\t"
                        "global_load_dwordx2 %1, %17, off sc0\n\t"
                        "global_load_dwordx2 %2, %18, off sc0\n\t"
                        "global_load_dwordx2 %3, %19, off sc0\n\t"
                        "global_load_dwordx2 %4, %20, off sc0\n\t"
                        "global_load_dwordx2 %5, %21, off sc0\n\t"
                        "global_load_dwordx2 %6, %22, off sc0\n\t"
                        "global_load_dwordx2 %7, %23, off sc0\n\t"
                        "s_waitcnt vmcnt(0)"
                        : "=&v"(v8), "=&v"(v9), "=&v"(v10), "=&v"(v11),
                          "=&v"(v12), "=&v"(v13), "=&v"(v14), "=&v"(v15),
                          "+v"(v0), "+v"(v1), "+v"(v2), "+v"(v3),
                          "+v"(v4), "+v"(v5), "+v"(v6), "+v"(v7)
                        : "v"((unsigned long long)(src + 8 * (HH / 2))),
                          "v"((unsigned long long)(src + 9 * (HH / 2))),
                          "v"((unsigned long long)(src + 10 * (HH / 2))),
                          "v"((unsigned long long)(src + 11 * (HH / 2))),
                          "v"((unsigned long long)(src + 12 * (HH / 2))),
                          "v"((unsigned long long)(src + 13 * (HH / 2))),
                          "v"((unsigned long long)(src + 14 * (HH / 2))),
                          "v"((unsigned long long)(src + 15 * (HH / 2))));
                    __builtin_amdgcn_sched_barrier(0);   // rule #18
                } else {
                    // guaranteed-progress round: R2's agent loads (IF$-served)
                    v0  = __hip_atomic_load(src +  0 * (HH / 2), __ATOMIC_RELAXED, __HIP_MEMORY_SCOPE_AGENT);
                    v1  = __hip_atomic_load(src +  1 * (HH / 2), __ATOMIC_RELAXED, __HIP_MEMORY_SCOPE_AGENT);
                    v2  = __hip_atomic_load(src +  2 * (HH / 2), __ATOMIC_RELAXED, __HIP_MEMORY_SCOPE_AGENT);
                    v3  = __hip_atomic_load(src +  3 * (HH / 2), __ATOMIC_RELAXED, __HIP_MEMORY_SCOPE_AGENT);
                    v4  = __hip_atomic_load(src +  4 * (HH / 2), __ATOMIC_RELAXED, __HIP_MEMORY_SCOPE_AGENT);
                    v5  = __hip_atomic_load(src +  5 * (HH / 2), __ATOMIC_RELAXED, __HIP_MEMORY_SCOPE_AGENT);
                    v6  = __hip_atomic_load(src +  6 * (HH / 2), __ATOMIC_RELAXED, __HIP_MEMORY_SCOPE_AGENT);
                    v7  = __hip_atomic_load(src +  7 * (HH / 2), __ATOMIC_RELAXED, __HIP_MEMORY_SCOPE_AGENT);
                    v8  = __hip_atomic_load(src +  8 * (HH / 2), __ATOMIC_RELAXED, __HIP_MEMORY_SCOPE_AGENT);
                    v9  = __hip_atomic_load(src +  9 * (HH / 2), __ATOMIC_RELAXED, __HIP_MEMORY_SCOPE_AGENT);
                    v10 = __hip_atomic_load(src + 10 * (HH / 2), __ATOMIC_RELAXED, __HIP_MEMORY_SCOPE_AGENT);
                    v11 = __hip_atomic_load(src + 11 * (HH / 2), __ATOMIC_RELAXED, __HIP_MEMORY_SCOPE_AGENT);
                    v12 = __hip_atomic_load(src + 12 * (HH / 2), __ATOMIC_RELAXED, __HIP_MEMORY_SCOPE_AGENT);
                    v13 = __hip_atomic_load(src + 13 * (HH / 2), __ATOMIC_RELAXED, __HIP_MEMORY_SCOPE_AGENT);
                    v14 = __hip_atomic_load(src + 14 * (HH / 2), __ATOMIC_RELAXED, __HIP_MEMORY_SCOPE_AGENT);
                    v15 = __hip_atomic_load(src + 15 * (HH / 2), __ATOMIC_RELAXED, __HIP_MEMORY_SCOPE_AGENT);
                }
                bool ok = ((unsigned)(v0  >> 32) == tg) & ((unsigned)(v1  >> 32) == tg)
                        & ((unsigned)(v2  >> 32) == tg) & ((unsigned)(v3  >> 32) == tg)
                        & ((unsigned)(v4  >> 32) == tg) & ((unsigned)(v5  >> 32) == tg)
                        & ((unsigned)(v6  >> 32) == tg) & ((unsigned)(v7  >> 32) == tg)
                        & ((unsigned)(v8  >> 32) == tg) & ((unsigned)(v9  >> 32) == tg)
                        & ((unsigned)(v10 >> 32) == tg) & ((unsigned)(v11 >> 32) == tg)
                        & ((unsigned)(v12 >> 32) == tg) & ((unsigned)(v13 >> 32) == tg)
                        & ((unsigned)(v14 >> 32) == tg) & ((unsigned)(v15 >> 32) == tg);
                if (ok) break;
                ++round;
            }
            *(unsigned int*)&hg[pcur][ 0][j8 * 2] = (unsigned int)v0;
            *(unsigned int*)&hg[pcur][ 1][j8 * 2] = (unsigned int)v1;
            *(unsigned int*)&hg[pcur][ 2][j8 * 2] = (unsigned int)v2;
            *(unsigned int*)&hg[pcur][ 3][j8 * 2] = (unsigned int)v3;
            *(unsigned int*)&hg[pcur][ 4][j8 * 2] = (unsigned int)v4;
            *(unsigned int*)&hg[pcur][ 5][j8 * 2] = (unsigned int)v5;
            *(unsigned int*)&hg[pcur][ 6][j8 * 2] = (unsigned int)v6;
            *(unsigned int*)&hg[pcur][ 7][j8 * 2] = (unsigned int)v7;
            *(unsigned int*)&hg[pcur][ 8][j8 * 2] = (unsigned int)v8;
            *(unsigned int*)&hg[pcur][ 9][j8 * 2] = (unsigned int)v9;
            *(unsigned int*)&hg[pcur][10][j8 * 2] = (unsigned int)v10;
            *(unsigned int*)&hg[pcur][11][j8 * 2] = (unsigned int)v11;
            *(unsigned int*)&hg[pcur][12][j8 * 2] = (unsigned int)v12;
            *(unsigned int*)&hg[pcur][13][j8 * 2] = (unsigned int)v13;
            *(unsigned int*)&hg[pcur][14][j8 * 2] = (unsigned int)v14;
            *(unsigned int*)&hg[pcur][15][j8 * 2] = (unsigned int)v15;
        }
        __syncthreads();   // B1: hg[pcur] + xsh[pcur] ready (only barrier/step)

        if (t < TT) {
            // pre = h_t.W_hh^T + x_t.W_xh^T + b_h ; block 0 interleaves the
            // full-K readout y_{t-1} = h_t.W_out^T reusing the SAME A-frags.
            const bool dordo = (c == 0) && (t >= 1);
            f32x4 acc0 = {0.f,0.f,0.f,0.f}, acc1 = {0.f,0.f,0.f,0.f};
            f32x4 ya   = {0.f,0.f,0.f,0.f};
            #pragma unroll
            for (int ks = 0; ks < 16; ks += 2) {
                f16x8 a0 = *(const f16x8*)&hg[pcur][l16][ks * 32 + quad * 8];
                f16x8 a1 = *(const f16x8*)&hg[pcur][l16][(ks + 1) * 32 + quad * 8];
                acc0 = __builtin_amdgcn_mfma_f32_16x16x32_f16(a0, bf[ks], acc0, 0, 0, 0);
                acc1 = __builtin_amdgcn_mfma_f32_16x16x32_f16(a1, bf[ks + 1], acc1, 0, 0, 0);
                if (dordo) {
                    ya = __builtin_amdgcn_mfma_f32_16x16x32_f16(a0, bfo2[ks], ya, 0, 0, 0);
                    ya = __builtin_amdgcn_mfma_f32_16x16x32_f16(a1, bfo2[ks + 1], ya, 0, 0, 0);
                }
            }
            #pragma unroll
            for (int ks = 0; ks < 4; ks += 2) {
                f16x8 a0 = *(const f16x8*)&xsh[pcur][l16][ks * 32 + quad * 8];
                f16x8 a1 = *(const f16x8*)&xsh[pcur][l16][(ks + 1) * 32 + quad * 8];
                acc0 = __builtin_amdgcn_mfma_f32_16x16x32_f16(a0, xbf[ks], acc0, 0, 0, 0);
                acc1 = __builtin_amdgcn_mfma_f32_16x16x32_f16(a1, xbf[ks + 1], acc1, 0, 0, 0);
            }
            // phi + leaky update; pack lane-pairs; fire-and-forget tagged u64
            unsigned long long* dst64 = hbuf + (size_t)((t + 1) & 1) * (BB * HH / 2);
            const unsigned long long tagw = ((unsigned long long)(unsigned)(t + 1)) << 32;
            unsigned int hb[4];
            #pragma unroll
            for (int reg = 0; reg < 4; ++reg) {
                float pre = acc0[reg] + acc1[reg] + biash;
                float z = 8.f * pre;
                float ph = (z > 20.f) ? pre : (__logf(1.f + __expf(z)) * 0.125f);
                float hn = 0.8f * hreg[reg] + 0.2f * ph;
                hreg[reg] = hn;
                hb[reg] = (unsigned int)__builtin_bit_cast(unsigned short, (f16)hn);
            }
            #pragma unroll
            for (int reg = 0; reg < 4; ++reg) {
                unsigned int ob = (unsigned int)__shfl_xor((int)hb[reg], 1, 64);
                if ((lane & 1) == 0) {
                    unsigned int pair = hb[reg] | (ob << 16);
                    size_t eidx = (size_t)(rowbase + quad * 4 + reg) * HH + jbase + myrow;
                    // agent/sc1 store (R2-proven): write-through local L2 -> IF$
                    __hip_atomic_store(dst64 + (eidx >> 1), tagw | (unsigned long long)pair,
                                       __ATOMIC_RELAXED, __HIP_MEMORY_SCOPE_AGENT);
                    // own-shard short-circuit into next-parity LDS buffer
                    *(unsigned int*)&hg[(t + 1) & 1][quad * 4 + reg][jbase + myrow] = pair;
                }
            }
            // plain-store readout (block 0 only; each y element written once)
            if (dordo) {
                #pragma unroll
                for (int reg = 0; reg < 4; ++reg)
                    yout[((size_t)(rowbase + quad * 4 + reg) * TT + (t - 1)) * OO + myrow]
                        = ya[reg] + biaso;
            }
        } else if (c == 0) {
            // ---- epilogue t==TT: y_{TT-1} from h_TT (hg[pcur=0]) ----
            f32x4 ya = {0.f,0.f,0.f,0.f};
            #pragma unroll
            for (int ks = 0; ks < 16; ++ks) {
                f16x8 a0 = *(const f16x8*)&hg[pcur][l16][ks * 32 + quad * 8];
                ya = __builtin_amdgcn_mfma_f32_16x16x32_f16(a0, bfo2[ks], ya, 0, 0, 0);
            }
            #pragma unroll
            for (int reg = 0; reg < 4; ++reg)
                yout[((size_t)(rowbase + quad * 4 + reg) * TT + (TT - 1)) * OO + myrow]
                    = ya[reg] + biaso;
        }
        // no B2: parity double-buffering; next iter's B1 is the only fence
    }
}

extern "C" void kernel_launch(void* const* d_in, const int* in_sizes, int n_in,
                              void* d_out, int out_size, void* d_ws, size_t ws_size,
                              hipStream_t stream)
{
    const float* x    = (const float*)d_in[0];
    const float* Wxh  = (const float*)d_in[1];
    const float* Whh  = (const float*)d_in[2];
    const float* bh   = (const float*)d_in[3];
    const float* Wout = (const float*)d_in[4];
    const float* bout = (const float*)d_in[5];
    float* yout = (float*)d_out;

    unsigned long long* hbuf = (unsigned long long*)d_ws;
    const size_t hbuf_bytes = (size_t)2 * BB * (HH / 2) * sizeof(unsigned long long); // 1 MB

    if (ws_size < hbuf_bytes) return;

    hipMemsetAsync(hbuf, 0, hbuf_bytes, stream);          // tags start 0; expected 1..512
    hipMemsetAsync(yout, 0, (size_t)out_size * sizeof(float), stream); // safety (fully overwritten)

    // 128 blocks x 256 threads (1 block/CU, ~42KB LDS) -> all co-resident.
    eirnn_persist<<<dim3(NB), dim3(256), 0, stream>>>(
        x, Wxh, Whh, bh, Wout, bout, yout, hbuf);
}

// Round 8
// 1377.453 us; speedup vs baseline: 1.0161x; 1.0161x over previous
//
#include <hip/hip_runtime.h>

// EIRNN: B=256,T=512,I=128,H=512,O=64; alpha=0.2, softplus beta=8, thresh=20.
// R9: ring-shrink experiment. Scoreboard: R2 1340 (IF$ polls) ~= R7 1334
// (L2 polls) ~= R8 1399 (atomics removed) -> step ~6300cy is insensitive to
// poll latency and readout atomics. Remaining suspects: T1 store-visibility
// hop (fixed cost) vs T2 max-over-7-producers jitter. R9 discriminates by
// shrinking the ring 8 -> 4 shards WITHOUT R3's VGPR cliff:
//   512-thread blocks (8 waves = 2 waves/SIMD -> 256-VGPR cap, m69), each
//   wave keeps EXACTLY R2's proven per-wave load (16 B-frags = 64 VGPR, one
//   16-col tile). Block covers 128 h-cols; NC=4, fan-in 3; 25% of exchange
//   short-circuits via LDS; remote poll words -25%; one 8-load poll round
//   per thread. Readout: back to R7's proven K-split atomicAdd (R8 proved
//   atomics cost ~nothing; saves 48 VGPR; symmetric across blocks -- R8's
//   asymmetric readout-in-c0 delayed c0's h-store and sat on the ring
//   critical path, the R8 lesson).
// Exchange protocol byte-identical to R7: tagged u64 {hi:tag=t+1, lo:2xf16}
// fire-and-forget sc1 stores; batched sc0 poll rounds (L2-servable) with
// every-4th-round agent fallback (placement-free progress, G16); parity
// double-buffer prevents overwrite-before-consume.
// Prediction: T2 -> 950-1150us; T1 -> neutral ~1300 (then attack store path).

#define BB 256
#define TT 512
#define II 128
#define HH 512
#define OO 64
#define RG 16   // batch rows per row-group
#define JC 128  // h-columns per shard block
#define NG 16   // row-groups
#define NC 4    // shard blocks per group
#define NB (NG * NC)

typedef _Float16 f16;
typedef f16 f16x8 __attribute__((ext_vector_type(8)));
typedef float f32x4 __attribute__((ext_vector_type(4)));

__global__ __launch_bounds__(512, 2)
void eirnn_persist(const float* __restrict__ x,
                   const float* __restrict__ Wxh,
                   const float* __restrict__ Whh,
                   const float* __restrict__ bh,
                   const float* __restrict__ Wout,
                   const float* __restrict__ bout,
                   float* __restrict__ yout,
                   unsigned long long* __restrict__ hbuf) // 2*(B*H/2) tagged u64
{
    const int tid  = threadIdx.x;
    const int bid  = blockIdx.x;
    const int wave = tid >> 6;        // 0..7
    const int lane = tid & 63;
    const int quad = lane >> 4;
    const int l16  = lane & 15;
    // XCD-clustered mapping (PERF HEURISTIC ONLY: presumed round-robin
    // dispatch xcd=bid&7; correctness is placement-free via agent fallback).
    // 64 blocks: 8 per presumed XCD = 2 groups x 4 shards.
    const int mm   = bid >> 3;                   // 0..7 within presumed XCD
    const int c    = mm >> 1;                    // shard 0..3
    const int r    = (bid & 7) * 2 + (mm & 1);   // group 0..15
    const int rowbase = r * RG;
    const int jbase   = c * JC;
    const int mycol   = wave * 16 + l16;         // 0..127 within block's range

    // double-buffered by step parity
    __shared__ __align__(16) f16 hg[2][RG][HH + 8];
    __shared__ __align__(16) f16 xsh[2][RG][II + 8];

    // ---- one-time: weight shards -> constant register B-fragments ----
    // B-frag: lane holds BT[n=lane&15][k=quad*8+j], j=0..7 (verified R0)
    f16x8 bf[16];   // W_hh shard col-tile (16 cols), K=512 -> 16 k-steps
    f16x8 xbf[4];   // W_xh shard col-tile, K=128 -> 4 k-steps
    f16x8 bfo[2];   // W_out: out-cols (wave&3)*16.., K-chunk c*128+(wave>>2)*64
    const int koff = c * JC + (wave >> 2) * 64;  // readout K offset
    const int ocol = (wave & 3) * 16 + l16;      // readout output col
    {
        const float* wp = Whh + (size_t)(jbase + mycol) * HH + quad * 8;
        #pragma unroll
        for (int ks = 0; ks < 16; ++ks) {
            float4 u = *(const float4*)(wp + ks * 32);
            float4 v = *(const float4*)(wp + ks * 32 + 4);
            f16x8 tv;
            tv[0]=(f16)u.x; tv[1]=(f16)u.y; tv[2]=(f16)u.z; tv[3]=(f16)u.w;
            tv[4]=(f16)v.x; tv[5]=(f16)v.y; tv[6]=(f16)v.z; tv[7]=(f16)v.w;
            bf[ks] = tv;
        }
        const float* wq = Wxh + (size_t)(jbase + mycol) * II + quad * 8;
        #pragma unroll
        for (int ks = 0; ks < 4; ++ks) {
            float4 u = *(const float4*)(wq + ks * 32);
            float4 v = *(const float4*)(wq + ks * 32 + 4);
            f16x8 tv;
            tv[0]=(f16)u.x; tv[1]=(f16)u.y; tv[2]=(f16)u.z; tv[3]=(f16)u.w;
            tv[4]=(f16)v.x; tv[5]=(f16)v.y; tv[6]=(f16)v.z; tv[7]=(f16)v.w;
            xbf[ks] = tv;
        }
        const float* wo = Wout + (size_t)ocol * HH + koff + quad * 8;
        #pragma unroll
        for (int ks = 0; ks < 2; ++ks) {
            float4 u = *(const float4*)(wo + ks * 32);
            float4 v = *(const float4*)(wo + ks * 32 + 4);
            f16x8 tv;
            tv[0]=(f16)u.x; tv[1]=(f16)u.y; tv[2]=(f16)u.z; tv[3]=(f16)u.w;
            tv[4]=(f16)v.x; tv[5]=(f16)v.y; tv[6]=(f16)v.z; tv[7]=(f16)v.w;
            bfo[ks] = tv;
        }
    }
    const float biash = bh[jbase + mycol];
    // bias added exactly once across all partials: shard 0, K-chunk 0 waves
    const float biaso = (c == 0 && (wave >> 2) == 0) ? bout[ocol] : 0.0f;

    // zero hg (t=0 uses h_0 = 0; buffer 1 fully written during iter 0)
    for (int p = tid; p < RG * (HH + 8); p += 512)
        ((unsigned int*)hg)[p] = 0u;

    // fp32 integrator state: lane owns h[m=quad*4+reg][jbase+mycol]
    float hreg[4] = {0.f, 0.f, 0.f, 0.f};

    // gather geometry: thread owns u64-col j8 at rows half*8..half*8+7
    const int j8     = tid & 255;    // u64-col 0..255 (f16 cols 2*j8, 2*j8+1)
    const int half   = tid >> 8;     // 0 or 1 -> rows 0-7 / 8-15
    const int gshard = j8 >> 6;      // producer shard of this u64-col (64/shard)

    // x prefetch for t=0: 512 threads x 1 float4 = 16 rows x 128 cols
    float4 xpf;
    xpf = ((const float4*)(x + ((size_t)(rowbase + (tid >> 5)) * TT + 0) * II))[tid & 31];

    __syncthreads();

    for (int t = 0; t <= TT; ++t) {
        const int pcur = t & 1;

        // ---- stage x_t from prefetch reg into xsh[pcur] ----
        if (t < TT) {
            f16* d0 = &xsh[pcur][tid >> 5][(tid & 31) * 4];
            d0[0]=(f16)xpf.x; d0[1]=(f16)xpf.y; d0[2]=(f16)xpf.z; d0[3]=(f16)xpf.w;
        }
        // ---- issue x_{t+1} prefetch; poll waits absorb it ----
        if (t + 1 < TT) {
            xpf = ((const float4*)(x + ((size_t)(rowbase + (tid >> 5)) * TT + (t + 1)) * II))[tid & 31];
        }
        // ---- gather: batched poll rounds, sc0 (L2) with agent fallback ----
        if (t >= 1 && gshard != c) {
            const unsigned long long* src = hbuf
                + (size_t)pcur * (BB * HH / 2)
                + (size_t)(rowbase + half * 8) * (HH / 2) + j8;
            const unsigned int tg = (unsigned)t;
            unsigned long long v0, v1, v2, v3, v4, v5, v6, v7;
            int round = 0;
            for (;;) {
                if ((round & 3) != 3) {
                    // sc0 batch: L1-bypass, L2-servable, 8 loads in flight
                    asm volatile(
                        "global_load_dwordx2 %0, %8, off sc0\n\t"
                        "global_load_dwordx2 %1, %9, off sc0\n\t"
                        "global_load_dwordx2 %2, %10, off sc0\n\t"
                        "global_load_dwordx2 %3, %11, off sc0\n\t"
                        "global_load_dwordx2 %4, %12, off sc0\n\t"
                        "global_load_dwordx2 %5, %13, off sc0\n\t"
                        "global_load_dwordx2 %6, %14, off sc0\n\t"
                        "global_load_dwordx2 %7, %15, off sc0\n\t"
                        "s_waitcnt vmcnt(0)"
                        : "=&v"(v0), "=&v"(v1), "=&v"(v2), "=&v"(v3),
                          "=&v"(v4), "=&v"(v5), "=&v"(v6), "=&v"(v7)
                        : "v"((unsigned long long)(src)),
                          "v"((unsigned long long)(src + 1 * (HH / 2))),
                          "v"((unsigned long long)(src + 2 * (HH / 2))),
                          "v"((unsigned long long)(src + 3 * (HH / 2))),
                          "v"((unsigned long long)(src + 4 * (HH / 2))),
                          "v"((unsigned long long)(src + 5 * (HH / 2))),
                          "v"((unsigned long long)(src + 6 * (HH / 2))),
                          "v"((unsigned long long)(src + 7 * (HH / 2))));
                    __builtin_amdgcn_sched_barrier(0);   // rule #18
                } else {
                    // guaranteed-progress round: R2's agent loads (IF$-served)
                    v0 = __hip_atomic_load(src + 0 * (HH / 2), __ATOMIC_RELAXED, __HIP_MEMORY_SCOPE_AGENT);
                    v1 = __hip_atomic_load(src + 1 * (HH / 2), __ATOMIC_RELAXED, __HIP_MEMORY_SCOPE_AGENT);
                    v2 = __hip_atomic_load(src + 2 * (HH / 2), __ATOMIC_RELAXED, __HIP_MEMORY_SCOPE_AGENT);
                    v3 = __hip_atomic_load(src + 3 * (HH / 2), __ATOMIC_RELAXED, __HIP_MEMORY_SCOPE_AGENT);
                    v4 = __hip_atomic_load(src + 4 * (HH / 2), __ATOMIC_RELAXED, __HIP_MEMORY_SCOPE_AGENT);
                    v5 = __hip_atomic_load(src + 5 * (HH / 2), __ATOMIC_RELAXED, __HIP_MEMORY_SCOPE_AGENT);
                    v6 = __hip_atomic_load(src + 6 * (HH / 2), __ATOMIC_RELAXED, __HIP_MEMORY_SCOPE_AGENT);
                    v7 = __hip_atomic_load(src + 7 * (HH / 2), __ATOMIC_RELAXED, __HIP_MEMORY_SCOPE_AGENT);
                }
                bool ok = ((unsigned)(v0 >> 32) == tg) & ((unsigned)(v1 >> 32) == tg)
                        & ((unsigned)(v2 >> 32) == tg) & ((unsigned)(v3 >> 32) == tg)
                        & ((unsigned)(v4 >> 32) == tg) & ((unsigned)(v5 >> 32) == tg)
                        & ((unsigned)(v6 >> 32) == tg) & ((unsigned)(v7 >> 32) == tg);
                if (ok) break;
                ++round;
            }
            const int rb = half * 8;
            *(unsigned int*)&hg[pcur][rb + 0][j8 * 2] = (unsigned int)v0;
            *(unsigned int*)&hg[pcur][rb + 1][j8 * 2] = (unsigned int)v1;
            *(unsigned int*)&hg[pcur][rb + 2][j8 * 2] = (unsigned int)v2;
            *(unsigned int*)&hg[pcur][rb + 3][j8 * 2] = (unsigned int)v3;
            *(unsigned int*)&hg[pcur][rb + 4][j8 * 2] = (unsigned int)v4;
            *(unsigned int*)&hg[pcur][rb + 5][j8 * 2] = (unsigned int)v5;
            *(unsigned int*)&hg[pcur][rb + 6][j8 * 2] = (unsigned int)v6;
            *(unsigned int*)&hg[pcur][rb + 7][j8 * 2] = (unsigned int)v7;
        }
        __syncthreads();   // B1: hg[pcur] + xsh[pcur] ready (only barrier/step)

        if (t < TT) {
            // pre = h_t.W_hh^T + x_t.W_xh^T + b_h
            f32x4 acc0 = {0.f,0.f,0.f,0.f}, acc1 = {0.f,0.f,0.f,0.f};
            #pragma unroll
            for (int ks = 0; ks < 16; ks += 2) {
                f16x8 a0 = *(const f16x8*)&hg[pcur][l16][ks * 32 + quad * 8];
                f16x8 a1 = *(const f16x8*)&hg[pcur][l16][(ks + 1) * 32 + quad * 8];
                acc0 = __builtin_amdgcn_mfma_f32_16x16x32_f16(a0, bf[ks], acc0, 0, 0, 0);
                acc1 = __builtin_amdgcn_mfma_f32_16x16x32_f16(a1, bf[ks + 1], acc1, 0, 0, 0);
            }
            #pragma unroll
            for (int ks = 0; ks < 4; ks += 2) {
                f16x8 a0 = *(const f16x8*)&xsh[pcur][l16][ks * 32 + quad * 8];
                f16x8 a1 = *(const f16x8*)&xsh[pcur][l16][(ks + 1) * 32 + quad * 8];
                acc0 = __builtin_amdgcn_mfma_f32_16x16x32_f16(a0, xbf[ks], acc0, 0, 0, 0);
                acc1 = __builtin_amdgcn_mfma_f32_16x16x32_f16(a1, xbf[ks + 1], acc1, 0, 0, 0);
            }
            // phi + leaky update; pack lane-pairs; fire-and-forget tagged u64
            unsigned long long* dst64 = hbuf + (size_t)((t + 1) & 1) * (BB * HH / 2);
            const unsigned long long tagw = ((unsigned long long)(unsigned)(t + 1)) << 32;
            unsigned int hb[4];
            #pragma unroll
            for (int reg = 0; reg < 4; ++reg) {
                float pre = acc0[reg] + acc1[reg] + biash;
                float z = 8.f * pre;
                float ph = (z > 20.f) ? pre : (__logf(1.f + __expf(z)) * 0.125f);
                float hn = 0.8f * hreg[reg] + 0.2f * ph;
                hreg[reg] = hn;
                hb[reg] = (unsigned int)__builtin_bit_cast(unsigned short, (f16)hn);
            }
            #pragma unroll
            for (int reg = 0; reg < 4; ++reg) {
                unsigned int ob = (unsigned int)__shfl_xor((int)hb[reg], 1, 64);
                if ((lane & 1) == 0) {
                    unsigned int pair = hb[reg] | (ob << 16);
                    size_t eidx = (size_t)(rowbase + quad * 4 + reg) * HH + jbase + mycol;
                    // agent/sc1 store (R2-proven): write-through local L2 -> IF$
                    __hip_atomic_store(dst64 + (eidx >> 1), tagw | (unsigned long long)pair,
                                       __ATOMIC_RELAXED, __HIP_MEMORY_SCOPE_AGENT);
                    // own-shard short-circuit into next-parity LDS buffer
                    *(unsigned int*)&hg[(t + 1) & 1][quad * 4 + reg][jbase + mycol] = pair;
                }
            }
        }

        // ---- readout partial: y_{t-1} += h_t[:, koff:koff+64] . W_out^T ----
        // (after the h-store: overlaps producers' store-propagation window)
        if (t >= 1) {
            f32x4 ya = {0.f,0.f,0.f,0.f};
            f16x8 a0 = *(const f16x8*)&hg[pcur][l16][koff + quad * 8];
            f16x8 a1 = *(const f16x8*)&hg[pcur][l16][koff + 32 + quad * 8];
            ya = __builtin_amdgcn_mfma_f32_16x16x32_f16(a0, bfo[0], ya, 0, 0, 0);
            ya = __builtin_amdgcn_mfma_f32_16x16x32_f16(a1, bfo[1], ya, 0, 0, 0);
            #pragma unroll
            for (int reg = 0; reg < 4; ++reg)
                atomicAdd(yout + ((size_t)(rowbase + quad * 4 + reg) * TT + (t - 1)) * OO + ocol,
                          ya[reg] + biaso);
        }
        // no B2: parity double-buffering; next iter's B1 is the only fence
    }
}

extern "C" void kernel_launch(void* const* d_in, const int* in_sizes, int n_in,
                              void* d_out, int out_size, void* d_ws, size_t ws_size,
                              hipStream_t stream)
{
    const float* x    = (const float*)d_in[0];
    const float* Wxh  = (const float*)d_in[1];
    const float* Whh  = (const float*)d_in[2];
    const float* bh   = (const float*)d_in[3];
    const float* Wout = (const float*)d_in[4];
    const float* bout = (const float*)d_in[5];
    float* yout = (float*)d_out;

    unsigned long long* hbuf = (unsigned long long*)d_ws;
    const size_t hbuf_bytes = (size_t)2 * BB * (HH / 2) * sizeof(unsigned long long); // 1 MB

    if (ws_size < hbuf_bytes) return;

    hipMemsetAsync(hbuf, 0, hbuf_bytes, stream);          // tags start 0; expected 1..512
    hipMemsetAsync(yout, 0, (size_t)out_size * sizeof(float), stream); // atomic targets

    // 64 blocks x 512 threads (8 waves, 2/SIMD, ~42KB LDS, VGPR<=256) -> co-resident.
    eirnn_persist<<<dim3(NB), dim3(512), 0, stream>>>(
        x, Wxh, Whh, bh, Wout, bout, yout, hbuf);
}